// Round 7
// baseline (466.929 us; speedup 1.0000x reference)
//
#include <hip/hip_runtime.h>
#include <math.h>

#define IN_DIM 28
#define BOND   10
#define OUT_D  10
#define BLOCK  256
#define SPT    2                 // samples per thread
#define CHUNK  (BLOCK * SPT)     // 512 samples per block -> grid 2048 = 8 blocks/CU
#define THRESH 18.0f             // fp32 sigmoid(c)==1.0f for c>=16.64 (e^-c<2^-24)

// R6 post-mortem: THRESH=18 fixed the slow-path blowup (kernel 151 -> ~60us)
// but the fast path is LATENCY-bound at 4 waves/SIMD (OccupancyPercent ~19%,
// grid=1024, VGPR=88): ~180 VALU cyc of compute per sample vs ~600-900 cyc
// load latency. This round doubles occupancy to 8 waves/SIMD:
//   - SPT=2 -> grid=2048 -> 8 blocks/CU = 32 waves/CU
//   - uv[] lives in LDS (broadcast b128 reads), not 56 VGPRs
//   - x loaded/consumed in two 7-quad batches (peak live ~28 regs)
//   - cold exact path RELOADS x from global so xq dies after the bound;
//     __launch_bounds__(256,8) caps VGPR at 64 (spills, if any, cold-path only)
//
// Fast path is a RIGOROUS per-sample bound, valid when (runtime-verified)
// all x >= 0 and all weights >= 0:
//     c[o] + bias[o] >= A*B + biasmin
//     A = sum_i x0[i]*v[i],  v[i] = min_b t0[i][b]           (A >= 0)
//     B = sum_j x1[j]*u[j],  u[j] = min_o sum_b t1[j][b][o]  (s1[o] >= B >= 0)
// If every lane of the wave clears THRESH, all 64 samples' outputs are
// provably exactly 1.0f (fp32 sigmoid saturation; absmax==0.0 across six
// rounds with different FMA orderings) -> coalesced float4 ones-stores.
// Any failure -> wave-uniform exact einsum from global (L2-hit) weights.
__global__ __launch_bounds__(BLOCK, 8) void tn_kernel(
    const float* __restrict__ x,     // [N, 56]
    const float* __restrict__ t0,    // [28,10]   (i,b)
    const float* __restrict__ t1,    // [28,10,10](j,b,o)
    const float* __restrict__ bias,  // [10]
    float* __restrict__ out,         // [N,10]
    int n_total)
{
    __shared__ __align__(16) float ssum[IN_DIM * OUT_D]; // [j][o] = sum_b t1[j][b][o]
    __shared__ __align__(16) float luv[2 * IN_DIM];      // [0..27]=v, [28..55]=u
    __shared__ float lmisc[2];                           // [0]=biasmin, [1]=wneg
    __shared__ int   lwn[BLOCK / 64];                    // per-wave neg flags

    const int tid = threadIdx.x;
    const int wid = tid >> 6;

    // ---- staging pass 1: v[i], ssum[j][o], biasmin, per-wave neg scan ----
    int localneg = 0;
    if (tid < IN_DIM) {                 // v[i] = min_b t0[i][b]; covers all of t0
        const float* __restrict__ p = t0 + tid * BOND;
        float m = 3.4e38f;
#pragma unroll
        for (int b = 0; b < BOND; ++b) {
            const float w = p[b];
            localneg |= (w < 0.0f);
            m = fminf(m, w);
        }
        luv[tid] = m;
    } else if (tid == 32) {
        float bm = bias[0];
#pragma unroll
        for (int o = 1; o < OUT_D; ++o) bm = fminf(bm, bias[o]);
        lmisc[0] = bm;
    }
    for (int idx = tid; idx < IN_DIM * OUT_D; idx += BLOCK) {  // covers all of t1
        const int j = idx / OUT_D;
        const int o = idx - j * OUT_D;
        const float* __restrict__ p = t1 + j * (BOND * OUT_D) + o;
        float s = 0.0f;
#pragma unroll
        for (int b = 0; b < BOND; ++b) {
            const float w = p[b * OUT_D];
            localneg |= (w < 0.0f);
            s += w;
        }
        ssum[idx] = s;
    }
    {   // no-init per-wave reduce: each wave's lane0 writes its own slot
        const unsigned long long bm = __ballot(localneg != 0);
        if ((tid & 63) == 0) lwn[wid] = (bm != 0ULL) ? 1 : 0;
    }
    __syncthreads();

    // ---- staging pass 2: u[j] = min_o ssum[j][o]; combine wneg ----
    if (tid < IN_DIM) {
        const float* __restrict__ p = ssum + tid * OUT_D;
        float m = p[0];
#pragma unroll
        for (int o = 1; o < OUT_D; ++o) m = fminf(m, p[o]);
        luv[IN_DIM + tid] = m;
    } else if (tid == 32) {
        lmisc[1] = (lwn[0] | lwn[1] | lwn[2] | lwn[3]) ? 1.0f : 0.0f;
    }
    __syncthreads();

    const float bmadd = lmisc[0];
    const float wn    = lmisc[1];
    const float4* __restrict__ uvp = reinterpret_cast<const float4*>(luv);

    const int base = blockIdx.x * CHUNK + tid;

#pragma unroll 1
    for (int k = 0; k < SPT; ++k) {
        const int n = base + k * BLOCK;
        const int nc = (n < n_total) ? n : (n_total - 1);   // clamp loads
        const float4* __restrict__ xrow =
            reinterpret_cast<const float4*>(x + (size_t)nc * (2 * IN_DIM));

        // batch 1: x0 half (7 quads in flight, then consumed -> regs die)
        float A = 0.0f, xmin = 0.0f;
        {
            float4 qa[7];
#pragma unroll
            for (int c = 0; c < 7; ++c) qa[c] = xrow[c];
#pragma unroll
            for (int c = 0; c < 7; ++c) {
                const float4 q = qa[c]; const float4 w = uvp[c];
                A = fmaf(q.x, w.x, A); A = fmaf(q.y, w.y, A);
                A = fmaf(q.z, w.z, A); A = fmaf(q.w, w.w, A);
                xmin = fminf(xmin, fminf(fminf(q.x, q.y), fminf(q.z, q.w)));
            }
        }
        // batch 2: x1 half
        float B = 0.0f;
        {
            float4 qb[7];
#pragma unroll
            for (int c = 0; c < 7; ++c) qb[c] = xrow[7 + c];
#pragma unroll
            for (int c = 0; c < 7; ++c) {
                const float4 q = qb[c]; const float4 w = uvp[7 + c];
                B = fmaf(q.x, w.x, B); B = fmaf(q.y, w.y, B);
                B = fmaf(q.z, w.z, B); B = fmaf(q.w, w.w, B);
                xmin = fminf(xmin, fminf(fminf(q.x, q.y), fminf(q.z, q.w)));
            }
        }

        const bool sat = (xmin >= 0.0f) && (wn == 0.0f) &&
                         (fmaf(A, B, bmadd) > THRESH);

        if (__all(sat)) {
            // Wave's 64 rows: contiguous 2560 B at out + wbase*10 (16B-aligned).
            const int wbase = n & ~63;          // multiple of 64 by construction
            const int l = tid & 63;
            if (wbase + 63 < n_total) {
                float4* __restrict__ wp =
                    reinterpret_cast<float4*>(out + (size_t)wbase * OUT_D);
                const float4 one4 = make_float4(1.0f, 1.0f, 1.0f, 1.0f);
                wp[l] = one4;                   // 160 float4: 64 + 64 + 32
                wp[64 + l] = one4;
                if (l < 32) wp[128 + l] = one4;
            } else if (n < n_total) {
                float2* __restrict__ op =
                    reinterpret_cast<float2*>(out + (size_t)n * OUT_D);
                const float2 one2 = make_float2(1.0f, 1.0f);
#pragma unroll
                for (int q = 0; q < 5; ++q) op[q] = one2;
            }
            continue;
        }

        // ===== exact path (wave-uniform branch; ~0.3% of waves) =====
        // Reload x from global (L2-hot) so the fast path's x regs are dead by
        // here; any register spills land in this cold path only.
        float xe[2 * IN_DIM];
#pragma unroll
        for (int c = 0; c < 14; ++c) {
            const float4 q = xrow[c];
            xe[4 * c + 0] = q.x; xe[4 * c + 1] = q.y;
            xe[4 * c + 2] = q.z; xe[4 * c + 3] = q.w;
        }
        float acc[OUT_D];
#pragma unroll
        for (int o = 0; o < OUT_D; ++o) acc[o] = bias[o];

#pragma unroll 1
        for (int b = 0; b < BOND; ++b) {
            const float* __restrict__ w0b = t0 + b;         // uniform -> s_load
            float hb = 0.0f;
#pragma unroll
            for (int i = 0; i < IN_DIM; ++i)
                hb = fmaf(xe[i], w0b[i * BOND], hb);

            const float* __restrict__ wb = t1 + b * OUT_D;  // uniform -> s_load
            float h1[OUT_D];
#pragma unroll
            for (int o = 0; o < OUT_D; ++o) h1[o] = 0.0f;
#pragma unroll
            for (int j = 0; j < IN_DIM; ++j) {
                const float x1j = xe[IN_DIM + j];
#pragma unroll
                for (int o = 0; o < OUT_D; ++o)
                    h1[o] = fmaf(x1j, wb[j * (BOND * OUT_D) + o], h1[o]);
            }
#pragma unroll
            for (int o = 0; o < OUT_D; ++o) acc[o] = fmaf(hb, h1[o], acc[o]);
        }

        if (n < n_total) {
            float2* __restrict__ op =
                reinterpret_cast<float2*>(out + (size_t)n * OUT_D);
#pragma unroll
            for (int o = 0; o < OUT_D; o += 2) {
                float2 r;
                r.x = 1.0f / (1.0f + __expf(-acc[o]));
                r.y = 1.0f / (1.0f + __expf(-acc[o + 1]));
                op[o >> 1] = r;
            }
        }
    }
}

extern "C" void kernel_launch(void* const* d_in, const int* in_sizes, int n_in,
                              void* d_out, int out_size, void* d_ws, size_t ws_size,
                              hipStream_t stream) {
    const float* x    = (const float*)d_in[0];
    const float* t0   = (const float*)d_in[1];
    const float* t1   = (const float*)d_in[2];
    const float* bias = (const float*)d_in[3];
    float* out        = (float*)d_out;

    const int n_total = in_sizes[0] / (2 * IN_DIM);
    const int grid = (n_total + CHUNK - 1) / CHUNK;
    tn_kernel<<<grid, BLOCK, 0, stream>>>(x, t0, t1, bias, out, n_total);
}

// Round 8
// 382.796 us; speedup vs baseline: 1.2198x; 1.2198x over previous
//
#include <hip/hip_runtime.h>
#include <math.h>

#define IN_DIM 28
#define BOND   10
#define OUT_D  10
#define BLOCK  256
#define WAVES  (BLOCK / 64)
#define SPT    2                   // tiles (of 64 samples) per wave
#define SAMPB  (BLOCK * SPT)       // 512 samples per block
#define ROWF   60                  // padded LDS row stride in floats (240 B, 16B-aligned)
#define THRESH 18.0f               // fp32 sigmoid(c)==1.0f for c>=16.64 (e^-c<2^-24)

// R7 post-mortem: launch_bounds(256,8) -> VGPR 32 -> hot-path spills (252 MB
// scratch writes), kernel 234us. Occupancy 19->55% bought nothing: NOT the
// limiter. Residual headline-kernel is constant ~229us (R5: 376-151, R7:
// 467-234), so the R2/R6 kernels were really ~104-117us = 2.5 TB/s effective
// on a 276 MB stream -- half the fill's 6.7 TB/s. Cause: per-lane row loads
// (stride 224B) touch 64 distinct cache lines per instruction (4x the L1/TA
// transactions of a coalesced stream).
//
// This round: wave-private LDS transpose. Each wave stages its 64-sample
// tile with 224 PERFECTLY COALESCED float4 loads (lane l loads quad s*64+l:
// consecutive lanes -> consecutive 16B, fill-like), ds_writes into a private
// LDS tile (row stride 240B), then each lane ds_read_b128's its own row
// (8-way bank conflict ~2.94x, hidden under the stream). Bound + ones-store
// + cold exact path unchanged (THRESH=18, wneg/xmin guards).
__global__ __launch_bounds__(BLOCK) void tn_kernel(
    const float* __restrict__ x,     // [N, 56]
    const float* __restrict__ t0,    // [28,10]   (i,b)
    const float* __restrict__ t1,    // [28,10,10](j,b,o)
    const float* __restrict__ bias,  // [10]
    float* __restrict__ out,         // [N,10]
    int n_total)
{
    __shared__ __align__(16) float xstage[WAVES][64 * ROWF];  // 61440 B
    __shared__ __align__(16) float ssum[IN_DIM * OUT_D];      // [j][o]=sum_b t1
    __shared__ __align__(16) float luv[2 * IN_DIM];           // v | u
    __shared__ float lmisc[2];                                // biasmin, wneg
    __shared__ int   lwn[WAVES];

    const int tid  = threadIdx.x;
    const int wid  = tid >> 6;
    const int lane = tid & 63;

    // ---- weight staging pass 1: v[i], ssum[j][o], biasmin, neg scan ----
    int localneg = 0;
    if (tid < IN_DIM) {
        const float* __restrict__ p = t0 + tid * BOND;
        float m = 3.4e38f;
#pragma unroll
        for (int b = 0; b < BOND; ++b) {
            const float w = p[b];
            localneg |= (w < 0.0f);
            m = fminf(m, w);
        }
        luv[tid] = m;
    } else if (tid == 32) {
        float bm = bias[0];
#pragma unroll
        for (int o = 1; o < OUT_D; ++o) bm = fminf(bm, bias[o]);
        lmisc[0] = bm;
    }
    for (int idx = tid; idx < IN_DIM * OUT_D; idx += BLOCK) {
        const int j = idx / OUT_D;
        const int o = idx - j * OUT_D;
        const float* __restrict__ p = t1 + j * (BOND * OUT_D) + o;
        float s = 0.0f;
#pragma unroll
        for (int b = 0; b < BOND; ++b) {
            const float w = p[b * OUT_D];
            localneg |= (w < 0.0f);
            s += w;
        }
        ssum[idx] = s;
    }
    {
        const unsigned long long bm = __ballot(localneg != 0);
        if (lane == 0) lwn[wid] = (bm != 0ULL) ? 1 : 0;
    }
    __syncthreads();

    // ---- weight staging pass 2: u[j] = min_o ssum[j][o]; combine wneg ----
    if (tid < IN_DIM) {
        const float* __restrict__ p = ssum + tid * OUT_D;
        float m = p[0];
#pragma unroll
        for (int o = 1; o < OUT_D; ++o) m = fminf(m, p[o]);
        luv[IN_DIM + tid] = m;
    } else if (tid == 32) {
        int a = 0;
#pragma unroll
        for (int wv = 0; wv < WAVES; ++wv) a |= lwn[wv];
        lmisc[1] = a ? 1.0f : 0.0f;
    }
    __syncthreads();

    const float bmadd = lmisc[0];
    const float wn    = lmisc[1];
    const float4* __restrict__ uvp = reinterpret_cast<const float4*>(luv);
    char* const wbuf = reinterpret_cast<char*>(&xstage[wid][0]);

    const size_t total_q = (size_t)n_total * 14;   // total quads in x

#pragma unroll 1
    for (int k = 0; k < SPT; ++k) {
        // tile = global 64-sample tile handled by this wave this iteration
        const int tile = (blockIdx.x * WAVES + wid) * SPT + k;
        const size_t sbase = (size_t)tile * 64;            // first sample
        if (sbase >= (size_t)n_total) break;
        const size_t qbase = sbase * 14;                   // first quad

        // ---- stage: 224 coalesced float4 loads -> wave-private LDS tile ----
        float4 st[4];
#pragma unroll
        for (int s = 0; s < 4; ++s) {
            const int q = s * 64 + lane;                   // 0..255, use <224
            size_t gq = qbase + (size_t)((q < 224) ? q : 0);
            if (gq >= total_q) gq = total_q - 1;           // tail clamp
            st[s] = reinterpret_cast<const float4*>(x)[gq];
        }
#pragma unroll
        for (int s = 0; s < 4; ++s) {
            const int q = s * 64 + lane;
            if (q < 224) {
                const int r = q / 14;                      // sample within tile
                const int c = q - r * 14;                  // quad within row
                *reinterpret_cast<float4*>(wbuf + r * (ROWF * 4) + c * 16) = st[s];
            }
        }
        // wave-private buffer: program order + compiler lgkmcnt orders the
        // ds_write -> ds_read dependency; no __syncthreads needed.

        // ---- read own row back; tier-1 bound ----
        char* const rowp = wbuf + lane * (ROWF * 4);
        float A = 0.0f, B = 0.0f, xmin = 0.0f;
#pragma unroll
        for (int c = 0; c < 7; ++c) {
            const float4 q = *reinterpret_cast<const float4*>(rowp + c * 16);
            const float4 w = uvp[c];
            A = fmaf(q.x, w.x, A); A = fmaf(q.y, w.y, A);
            A = fmaf(q.z, w.z, A); A = fmaf(q.w, w.w, A);
            xmin = fminf(xmin, fminf(fminf(q.x, q.y), fminf(q.z, q.w)));
        }
#pragma unroll
        for (int c = 7; c < 14; ++c) {
            const float4 q = *reinterpret_cast<const float4*>(rowp + c * 16);
            const float4 w = uvp[c];
            B = fmaf(q.x, w.x, B); B = fmaf(q.y, w.y, B);
            B = fmaf(q.z, w.z, B); B = fmaf(q.w, w.w, B);
            xmin = fminf(xmin, fminf(fminf(q.x, q.y), fminf(q.z, q.w)));
        }

        const bool sat = (xmin >= 0.0f) && (wn == 0.0f) &&
                         (fmaf(A, B, bmadd) > THRESH);

        const int n = (int)sbase + lane;                   // this lane's sample

        if (__all(sat)) {
            // tile's 64 rows: contiguous 2560 B at out + sbase*10 (16B-aligned)
            if (sbase + 63 < (size_t)n_total) {
                float4* __restrict__ wp =
                    reinterpret_cast<float4*>(out + sbase * OUT_D);
                const float4 one4 = make_float4(1.0f, 1.0f, 1.0f, 1.0f);
                wp[lane] = one4;                 // 160 float4: 64 + 64 + 32
                wp[64 + lane] = one4;
                if (lane < 32) wp[128 + lane] = one4;
            } else if (n < n_total) {
                float2* __restrict__ op =
                    reinterpret_cast<float2*>(out + (size_t)n * OUT_D);
                const float2 one2 = make_float2(1.0f, 1.0f);
#pragma unroll
                for (int q = 0; q < 5; ++q) op[q] = one2;
            }
            continue;
        }

        // ===== exact path (wave-uniform branch; ~0.3% of waves) =====
        // Reload this lane's row from global (L2-hot: just streamed).
        const int nc = (n < n_total) ? n : (n_total - 1);
        const float4* __restrict__ xrow =
            reinterpret_cast<const float4*>(x + (size_t)nc * (2 * IN_DIM));
        float xe[2 * IN_DIM];
#pragma unroll
        for (int c = 0; c < 14; ++c) {
            const float4 q = xrow[c];
            xe[4 * c + 0] = q.x; xe[4 * c + 1] = q.y;
            xe[4 * c + 2] = q.z; xe[4 * c + 3] = q.w;
        }
        float acc[OUT_D];
#pragma unroll
        for (int o = 0; o < OUT_D; ++o) acc[o] = bias[o];

#pragma unroll 1
        for (int b = 0; b < BOND; ++b) {
            const float* __restrict__ w0b = t0 + b;         // uniform -> s_load
            float hb = 0.0f;
#pragma unroll
            for (int i = 0; i < IN_DIM; ++i)
                hb = fmaf(xe[i], w0b[i * BOND], hb);

            const float* __restrict__ wb = t1 + b * OUT_D;  // uniform -> s_load
            float h1[OUT_D];
#pragma unroll
            for (int o = 0; o < OUT_D; ++o) h1[o] = 0.0f;
#pragma unroll
            for (int j = 0; j < IN_DIM; ++j) {
                const float x1j = xe[IN_DIM + j];
#pragma unroll
                for (int o = 0; o < OUT_D; ++o)
                    h1[o] = fmaf(x1j, wb[j * (BOND * OUT_D) + o], h1[o]);
            }
#pragma unroll
            for (int o = 0; o < OUT_D; ++o) acc[o] = fmaf(hb, h1[o], acc[o]);
        }

        if (n < n_total) {
            float2* __restrict__ op =
                reinterpret_cast<float2*>(out + (size_t)n * OUT_D);
#pragma unroll
            for (int o = 0; o < OUT_D; o += 2) {
                float2 r;
                r.x = 1.0f / (1.0f + __expf(-acc[o]));
                r.y = 1.0f / (1.0f + __expf(-acc[o + 1]));
                op[o >> 1] = r;
            }
        }
    }
}

extern "C" void kernel_launch(void* const* d_in, const int* in_sizes, int n_in,
                              void* d_out, int out_size, void* d_ws, size_t ws_size,
                              hipStream_t stream) {
    const float* x    = (const float*)d_in[0];
    const float* t0   = (const float*)d_in[1];
    const float* t1   = (const float*)d_in[2];
    const float* bias = (const float*)d_in[3];
    float* out        = (float*)d_out;

    const int n_total = in_sizes[0] / (2 * IN_DIM);
    const int grid = (n_total + SAMPB - 1) / SAMPB;
    tn_kernel<<<grid, BLOCK, 0, stream>>>(x, t0, t1, bias, out, n_total);
}